// Round 18
// baseline (85.082 us; speedup 1.0000x reference)
//
#include <hip/hip_runtime.h>
#include <math.h>

// DecomposedFrequencyLearning: NaN-fill -> rfft(4096) -> 4x freq mask -> irfft
// x[32,4096,64] f32  ->  out[4,32,4096,64] f32
//
// R18 = R16 exactly (best: 84.0us; pad layout, fused fill+fwd+4x(mask+inv)
// -> dense fp16 ws2 rows; expand kernel) + ONE new variable: a one-time
// s_sleep stagger (~2900 cyc ~ half an LDS-exchange phase) for half the WGs.
// Theory: co-resident WGs run phase-locked (convoy) -- LDS read-bursts all
// collide, then LDS idles while everyone computes (VALUBusy 30%, LDS-pipe
// math says phases should cost 1.3us but measure ~2.5us). Stagger makes the
// 4 WGs/CU antiphase so LDS and VALU interleave.
// R17 lesson: b128 swizzle raised conflicts 4x and was net-null -> reverted.
// No occupancy attrs (VGPR-64 collapse + spill: R2/R4/R7). fp16 park
// verified (absmax 0.031 << 0.099). pad(v)=v+(v>>4).

namespace {

constexpr int NFFT = 4096;
constexpr int NT   = 256;
constexpr int NB   = 32;
constexpr int NC   = 64;
constexpr int KF   = 4;

typedef __fp16 h2 __attribute__((ext_vector_type(2)));
typedef float  f4 __attribute__((ext_vector_type(4)));

__device__ __forceinline__ int pad(int i) { return i + (i >> 4); }

// LDS-only barrier: wave drains its own LDS ops, then syncs. Global stores
// stay in flight across it.
__device__ __forceinline__ void lds_barrier(){
    asm volatile("s_waitcnt lgkmcnt(0)" ::: "memory");
    __builtin_amdgcn_s_barrier();
}

__device__ __forceinline__ unsigned packh(float x, float y){
    h2 h = __builtin_amdgcn_cvt_pkrtz(x, y);   // v_cvt_pkrtz_f16_f32
    return __builtin_bit_cast(unsigned, h);
}
__device__ __forceinline__ float2 unpackh(unsigned u){
    h2 h = __builtin_bit_cast(h2, u);
    return make_float2((float)h.x, (float)h.y);
}

__device__ __forceinline__ float2 cadd(float2 a, float2 b){ return make_float2(a.x+b.x, a.y+b.y); }
__device__ __forceinline__ float2 csub(float2 a, float2 b){ return make_float2(a.x-b.x, a.y-b.y); }
__device__ __forceinline__ float2 cmul(float2 a, float2 b){
    return make_float2(fmaf(a.x,b.x,-(a.y*b.y)), fmaf(a.x,b.y, a.y*b.x));
}
// a * conj(b)
__device__ __forceinline__ float2 cmulc(float2 a, float2 b){
    return make_float2(fmaf(a.x,b.x, a.y*b.y), fmaf(a.y,b.x,-(a.x*b.y)));
}

__device__ __forceinline__ void bf4_fwd(float2&a,float2&b,float2&c,float2&d){
    float2 t0=cadd(a,c), t1=csub(a,c), t2=cadd(b,d), t3=csub(b,d);
    float2 mi3=make_float2(t3.y,-t3.x);          // -i*t3
    a=cadd(t0,t2); b=cadd(t1,mi3); c=csub(t0,t2); d=csub(t1,mi3);
}
__device__ __forceinline__ void bf4_inv(float2&a,float2&b,float2&c,float2&d){
    float2 t0=cadd(a,c), t1=csub(a,c), t2=cadd(b,d), t3=csub(b,d);
    float2 pi3=make_float2(-t3.y,t3.x);          // +i*t3
    a=cadd(t0,t2); b=cadd(t1,pi3); c=csub(t0,t2); d=csub(t1,pi3);
}
__device__ __forceinline__ void grp_fwd(float2&a,float2&b,float2&c,float2&d,
                                        float2 w1, float2 w2, float2 w3){
    bf4_fwd(a,b,c,d);
    b=cmul(b,w1); c=cmul(c,w2); d=cmul(d,w3);
}
__device__ __forceinline__ void xgrp_fwd(float2&a,float2&b,float2&c,float2&d, float2 w1){
    float2 w2=cmul(w1,w1), w3=cmul(w2,w1);
    grp_fwd(a,b,c,d,w1,w2,w3);
}
__device__ __forceinline__ void grp_inv(float2&a,float2&b,float2&c,float2&d,
                                        float2 w1, float2 w2, float2 w3){
    b=cmulc(b,w1); c=cmulc(c,w2); d=cmulc(d,w3);
    bf4_inv(a,b,c,d);
}
__device__ __forceinline__ void xgrp_inv(float2&a,float2&b,float2&c,float2&d, float2 w1){
    float2 w2=cmul(w1,w1), w3=cmul(w2,w1);
    grp_inv(a,b,c,d,w1,w2,w3);
}

// ========== Fused kernel: fill + forward + 4x(mask + inverse) ==========
// COAL=true: dense fp16 rows to ws2[k][b][pair][t]. false: scattered f32 out.
template<bool COAL>
__global__ __launch_bounds__(NT)
void dfl_fused(const float* __restrict__ x,
               const int* __restrict__ taus,
               const int* __restrict__ mus,
               float* __restrict__ out,
               unsigned* __restrict__ ws2)
{
    __shared__ unsigned bufh[NFFT + NFFT/16];   // 17408 B, half2-packed
    __shared__ unsigned spech[NFFT + NFFT/16];  // 17408 B, half2-packed park
    __shared__ float2 wtab[512];                // 4096 B  (total 38912)

    const int tid = threadIdx.x;
    const int l    = ((blockIdx.x & 7) << 7) | (blockIdx.x >> 3);  // XCD swizzle
    const int b    = l >> 5;
    const int pair = l & 31;
    const int c0   = pair << 1;
    const float QNAN = __uint_as_float(0x7fc00000u);

    // ---- convoy-breaking stagger: half the WGs sleep ~2900 cyc (half an
    // LDS-exchange phase) so co-resident WGs run antiphase: one WG's LDS
    // burst overlaps another's VALU burst instead of colliding.
    if ((blockIdx.x >> 3) & 1) {
        __builtin_amdgcn_s_sleep(23);   // ~23*64 = 1472 cyc
        __builtin_amdgcn_s_sleep(23);   // total ~2944 cyc
    }

    // w(j) = exp(-2*pi*i*j/4096), j<512
    for (int j = tid; j < 512; j += NT) {
        float s, c; sincosf(-3.14159265358979f * (float)j / 2048.0f, &s, &c);
        wtab[j] = make_float2(c, s);
    }

    // scan scratch aliases the (not-yet-used) spectrum region
    float2* chLast  = reinterpret_cast<float2*>(spech);        // [256]
    float2* chFirst = reinterpret_cast<float2*>(spech) + 256;  // [256]

    // ---- load + in-chunk forward fill (thread t owns times [16t,16t+16)) ----
    const float* xb = x + ((size_t)b * NFFT) * NC + c0;
    float2 z[16];
    float2 last = make_float2(QNAN, QNAN), first = make_float2(QNAN, QNAN);
    #pragma unroll
    for (int j = 0; j < 16; ++j) {
        float2 v = *reinterpret_cast<const float2*>(xb + (size_t)(16*tid + j) * NC);
        if (first.x != first.x && v.x == v.x) first.x = v.x;
        if (first.y != first.y && v.y == v.y) first.y = v.y;
        if (v.x == v.x) last.x = v.x; else v.x = last.x;
        if (v.y == v.y) last.y = v.y; else v.y = last.y;
        z[j] = v;                               // NaN only in leading run
    }
    chLast[tid] = last;
    chFirst[tid] = first;
    lds_barrier();                              // S1

    // last observed before this chunk
    float2 pre = make_float2(QNAN, QNAN);
    for (int kk = tid - 1; kk >= 0; --kk) {
        float2 s2 = chLast[kk];
        if (pre.x != pre.x) pre.x = s2.x;
        if (pre.y != pre.y) pre.y = s2.y;
        if (pre.x == pre.x && pre.y == pre.y) break;
    }
    // globally first observed (backward-fill value for the leading prefix)
    float2 gfirst = make_float2(QNAN, QNAN);
    for (int kk = 0; kk < NT; ++kk) {
        float2 s2 = chFirst[kk];
        if (gfirst.x != gfirst.x) gfirst.x = s2.x;
        if (gfirst.y != gfirst.y) gfirst.y = s2.y;
        if (gfirst.x == gfirst.x && gfirst.y == gfirst.y) break;
    }
    if (gfirst.x != gfirst.x) gfirst.x = 0.f;   // all-NaN -> 0
    if (gfirst.y != gfirst.y) gfirst.y = 0.f;
    const float fx = (pre.x == pre.x) ? pre.x : gfirst.x;
    const float fy = (pre.y == pre.y) ? pre.y : gfirst.y;
    const float scale = 1.0f / (float)NFFT;     // prescale -> fp16-safe range
    #pragma unroll
    for (int j = 0; j < 16; ++j) {
        if (z[j].x != z[j].x) z[j].x = fx;
        if (z[j].y != z[j].y) z[j].y = fy;
        z[j].x *= scale; z[j].y *= scale;
    }

    // ---- per-thread twiddle bases ----
    const float2 wm = wtab[tid];                        // w(m)
    float2 q2 = cmul(wm, wm);
    const float2 w4m = cmul(q2, q2);                    // w(4m)
    const float2 w16r = wtab[16 * (tid & 15)];          // w(16r)
    float2 q3 = cmul(w16r, w16r);
    const float2 w64r = cmul(q3, q3);                   // w(64r)

    const float2 W1 = make_float2( 0.92387953251f,-0.38268343236f); // w(256)
    const float2 W2 = make_float2( 0.70710678119f,-0.70710678119f); // w(512)
    const float2 W3 = make_float2( 0.38268343236f,-0.92387953251f); // w(768)
    const float2 W4 = make_float2( 0.f,-1.f);                       // w(1024)
    const float2 W6 = make_float2(-0.70710678119f,-0.70710678119f); // w(1536)
    const float2 W9 = make_float2(-0.92387953251f, 0.38268343236f); // w(2304)

    lds_barrier();                              // S2: scans done, spech reusable

    // ---- write x_clean/N at P3 (natural time), fp16-packed ----
    #pragma unroll
    for (int j = 0; j < 16; ++j) bufh[pad(16*tid + j)] = packh(z[j].x, z[j].y);
    lds_barrier();                              // S3

    // ================= forward DIF =================
    // phase A on P1 (n = m + 256j)
    #pragma unroll
    for (int j = 0; j < 16; ++j) z[j] = unpackh(bufh[pad(tid + 256*j)]);
    xgrp_fwd(z[0],z[4],z[8],z[12], wm);
    xgrp_fwd(z[1],z[5],z[9],z[13], cmul(wm,W1));
    xgrp_fwd(z[2],z[6],z[10],z[14], cmul(wm,W2));
    xgrp_fwd(z[3],z[7],z[11],z[15], cmul(wm,W3));
    {   float2 w1=w4m, w2=cmul(w1,w1), w3=cmul(w2,w1);
        grp_fwd(z[0],z[1],z[2],z[3],  w1,w2,w3);
        grp_fwd(z[4],z[5],z[6],z[7],  w1,w2,w3);
        grp_fwd(z[8],z[9],z[10],z[11],w1,w2,w3);
        grp_fwd(z[12],z[13],z[14],z[15],w1,w2,w3);
    }
    #pragma unroll
    for (int j = 0; j < 16; ++j) bufh[pad(tid + 256*j)] = packh(z[j].x, z[j].y);
    lds_barrier();                              // S4

    // phase B on P2 (n = (m>>4)*256 + (m&15) + 16j)
    const int p2b = ((tid >> 4) << 8) + (tid & 15);
    #pragma unroll
    for (int j = 0; j < 16; ++j) z[j] = unpackh(bufh[pad(p2b + 16*j)]);
    xgrp_fwd(z[0],z[4],z[8],z[12], w16r);
    xgrp_fwd(z[1],z[5],z[9],z[13], cmul(w16r,W1));
    xgrp_fwd(z[2],z[6],z[10],z[14], cmul(w16r,W2));
    xgrp_fwd(z[3],z[7],z[11],z[15], cmul(w16r,W3));
    {   float2 w1=w64r, w2=cmul(w1,w1), w3=cmul(w2,w1);
        grp_fwd(z[0],z[1],z[2],z[3],  w1,w2,w3);
        grp_fwd(z[4],z[5],z[6],z[7],  w1,w2,w3);
        grp_fwd(z[8],z[9],z[10],z[11],w1,w2,w3);
        grp_fwd(z[12],z[13],z[14],z[15],w1,w2,w3);
    }
    #pragma unroll
    for (int j = 0; j < 16; ++j) bufh[pad(p2b + 16*j)] = packh(z[j].x, z[j].y);
    lds_barrier();                              // S5

    // phase C on P3 (n = 16m + j)
    #pragma unroll
    for (int j = 0; j < 16; ++j) z[j] = unpackh(bufh[pad(16*tid + j)]);
    bf4_fwd(z[0],z[4],z[8],z[12]);
    grp_fwd(z[1],z[5],z[9],z[13], W1,W2,W3);
    grp_fwd(z[2],z[6],z[10],z[14], W2,W4,W6);
    grp_fwd(z[3],z[7],z[11],z[15], W3,W6,W9);
    bf4_fwd(z[0],z[1],z[2],z[3]);
    bf4_fwd(z[4],z[5],z[6],z[7]);
    bf4_fwd(z[8],z[9],z[10],z[11]);
    bf4_fwd(z[12],z[13],z[14],z[15]);

    // ---- park spectrum (already /N) in LDS, fp16-packed, own P3 slots ----
    #pragma unroll
    for (int j = 0; j < 16; ++j) spech[pad(16*tid + j)] = packh(z[j].x, z[j].y);

    // digit-reverse of tid (4 base-4 digits)
    const int revtid = ((tid & 3) << 6) | (((tid >> 2) & 3) << 4)
                     | (((tid >> 4) & 3) << 2) | (tid >> 6);

    // ================= per-filter inverse DIT =================
    #pragma unroll 1
    for (int k = 0; k < KF; ++k) {
        const int tau = taus[k];
        const int mu  = mus[k];
        lds_barrier();          // prior bufh reads done; stores stay in flight

        // mask + unpack (own P3 slots)
        #pragma unroll
        for (int j = 0; j < 16; ++j) {
            const int r = revtid + ((j & 3) << 10) + ((j >> 2) << 8);
            const int f = (r <= 2048) ? r : (NFFT - r);
            const bool keep = (mu == 1) ? (f < tau) : (f >= tau);
            z[j] = keep ? unpackh(spech[pad(16*tid + j)]) : make_float2(0.f, 0.f);
        }
        // stage0: Y-groups, no twiddle
        bf4_inv(z[0],z[1],z[2],z[3]);
        bf4_inv(z[4],z[5],z[6],z[7]);
        bf4_inv(z[8],z[9],z[10],z[11]);
        bf4_inv(z[12],z[13],z[14],z[15]);
        // stage1: X-groups, k1 = 256*jp (constants)
        bf4_inv(z[0],z[4],z[8],z[12]);
        grp_inv(z[1],z[5],z[9],z[13], W1,W2,W3);
        grp_inv(z[2],z[6],z[10],z[14], W2,W4,W6);
        grp_inv(z[3],z[7],z[11],z[15], W3,W6,W9);
        #pragma unroll
        for (int j = 0; j < 16; ++j) bufh[pad(16*tid + j)] = packh(z[j].x, z[j].y);
        lds_barrier();

        #pragma unroll
        for (int j = 0; j < 16; ++j) z[j] = unpackh(bufh[pad(p2b + 16*j)]);
        // stage2: Y-groups, k1 = 64r
        {   float2 w1=w64r, w2=cmul(w1,w1), w3=cmul(w2,w1);
            grp_inv(z[0],z[1],z[2],z[3],  w1,w2,w3);
            grp_inv(z[4],z[5],z[6],z[7],  w1,w2,w3);
            grp_inv(z[8],z[9],z[10],z[11],w1,w2,w3);
            grp_inv(z[12],z[13],z[14],z[15],w1,w2,w3);
        }
        // stage3: X-groups, k1 = 16r + 256*jp
        xgrp_inv(z[0],z[4],z[8],z[12], w16r);
        xgrp_inv(z[1],z[5],z[9],z[13], cmul(w16r,W1));
        xgrp_inv(z[2],z[6],z[10],z[14], cmul(w16r,W2));
        xgrp_inv(z[3],z[7],z[11],z[15], cmul(w16r,W3));
        #pragma unroll
        for (int j = 0; j < 16; ++j) bufh[pad(p2b + 16*j)] = packh(z[j].x, z[j].y);
        lds_barrier();

        #pragma unroll
        for (int j = 0; j < 16; ++j) z[j] = unpackh(bufh[pad(tid + 256*j)]);
        // stage4: Y-groups, k1 = 4m
        {   float2 w1=w4m, w2=cmul(w1,w1), w3=cmul(w2,w1);
            grp_inv(z[0],z[1],z[2],z[3],  w1,w2,w3);
            grp_inv(z[4],z[5],z[6],z[7],  w1,w2,w3);
            grp_inv(z[8],z[9],z[10],z[11],w1,w2,w3);
            grp_inv(z[12],z[13],z[14],z[15],w1,w2,w3);
        }
        // stage5: X-groups, k1 = m + 256*jp
        xgrp_inv(z[0],z[4],z[8],z[12], wm);
        xgrp_inv(z[1],z[5],z[9],z[13], cmul(wm,W1));
        xgrp_inv(z[2],z[6],z[10],z[14], cmul(wm,W2));
        xgrp_inv(z[3],z[7],z[11],z[15], cmul(wm,W3));

        if (COAL) {
            // dense fp16 row [k][b][pair][t]; 256B contiguous per wave-inst;
            // stays in flight across the next filter's lds_barrier
            unsigned* orow = ws2 + ((size_t)((k*NB + b)*32 + pair)) * NFFT;
            #pragma unroll
            for (int j = 0; j < 16; ++j)
                orow[tid + 256*j] = packh(z[j].x, z[j].y);
        } else {
            float* ob = out + ((size_t)(k*NB + b) * NFFT) * NC + c0;
            #pragma unroll
            for (int j = 0; j < 16; ++j) {
                const int t = tid + 256*j;
                *reinterpret_cast<float2*>(ob + (size_t)t * NC) = z[j];
            }
        }
    }
}

// ===================== transpose-expand =====================
// ws2[k][b][pair][t] fp16-packed -> out[k][b][t][c] f32, all coalesced.
__global__ __launch_bounds__(NT)
void dfl_expand(const unsigned* __restrict__ ws2, float* __restrict__ out)
{
    __shared__ unsigned tile[32][257];          // 32 pairs x 256 t (+pad)

    const int tid = threadIdx.x;
    const int wg  = ((blockIdx.x & 7) << 8) | (blockIdx.x >> 3);  // XCD swizzle
    const int tb  = wg & 15;                    // t-block (256 t each)
    const int kb  = wg >> 4;                    // k*NB + b, 0..127
    const int t0  = tb << 8;

    const unsigned* src = ws2 + ((size_t)kb * 32) * NFFT + t0;
    // load 32 rows x 256 u32 as uint4 (16B/lane, dense)
    #pragma unroll
    for (int i = 0; i < 8; ++i) {
        const int g   = i * NT + tid;           // uint4 index, 0..2047
        const int row = g >> 6;                 // 64 uint4 per row
        const int t4  = (g & 63) << 2;
        uint4 v = *reinterpret_cast<const uint4*>(src + (size_t)row * NFFT + t4);
        tile[row][t4+0] = v.x; tile[row][t4+1] = v.y;
        tile[row][t4+2] = v.z; tile[row][t4+3] = v.w;
    }
    __syncthreads();

    // store: out rows, float4 = 4 channels (2 pairs) per lane; a wave covers
    // 4 full t-rows = 1KiB contiguous. Nontemporal: out is never re-read.
    float* ob = out + ((size_t)kb * NFFT + t0) * NC;
    #pragma unroll
    for (int j = 0; j < 16; ++j) {
        const int g    = j * NT + tid;          // float4 index, 0..4095
        const int tloc = g >> 4;                // 16 float4 per t-row
        const int q    = g & 15;                // pair-pair index
        float2 a  = unpackh(tile[2*q    ][tloc]);
        float2 bb = unpackh(tile[2*q + 1][tloc]);
        f4 v = {a.x, a.y, bb.x, bb.y};
        __builtin_nontemporal_store(
            v, reinterpret_cast<f4*>(ob + (size_t)tloc * NC + 4*q));
    }
}

} // namespace

extern "C" void kernel_launch(void* const* d_in, const int* in_sizes, int n_in,
                              void* d_out, int out_size, void* d_ws, size_t ws_size,
                              hipStream_t stream) {
    (void)in_sizes; (void)n_in; (void)out_size;
    const float* x  = (const float*)d_in[0];
    const int* taus = (const int*)d_in[1];
    const int* mus  = (const int*)d_in[2];
    float* out      = (float*)d_out;
    unsigned* ws2   = (unsigned*)d_ws;          // staging: 64 MiB
    const size_t need = (size_t)64 << 20;

    if (ws_size >= need) {
        dfl_fused<true><<<dim3(NB * NC / 2), dim3(NT), 0, stream>>>(
            x, taus, mus, out, ws2);
        dfl_expand<<<dim3(KF * NB * 16), dim3(NT), 0, stream>>>(ws2, out);
    } else {
        dfl_fused<false><<<dim3(NB * NC / 2), dim3(NT), 0, stream>>>(
            x, taus, mus, out, nullptr);
    }
}

// Round 19
// 84.006 us; speedup vs baseline: 1.0128x; 1.0128x over previous
//
#include <hip/hip_runtime.h>
#include <math.h>

// DecomposedFrequencyLearning: NaN-fill -> rfft(4096) -> 4x freq mask -> irfft
// x[32,4096,64] f32  ->  out[4,32,4096,64] f32
//
// R19 = R16 (best: 84.0us) + barrier diet:
//  1) S2+S3 merged: the scan-done barrier and bufh-written barrier guard
//     DIFFERENT buffers (spech scratch vs bufh) -> one barrier. 17->16 phases.
//  2) per-filter mask+stage0+stage1 moved BEFORE the loop-top barrier: they
//     touch only own-thread spech slots (no cross-thread hazard), so this
//     VALU burst overlaps other waves' barrier arrival (skew absorption).
// Cross-round model being tested: every design lands at ~250 WG-phases/us
// (R12 21.5k->87us, R16 21.5k->84us, R11-fwd 5k->14us) independent of
// occupancy/barrier-flavor/swizzle. Removing a phase should give ~-4us.
// Null => declare structural floor.
// Nulls so far: raw-barrier semantics (R10), b128 swizzle (R17, conflicts
// 4x worse), s_sleep stagger (R18). Wins: dense stores (R12), fusion (R16).
// No occupancy attrs (VGPR-64 collapse + spill: R2/R4/R7). fp16 park
// verified (absmax 0.031 << 0.099). pad(v)=v+(v>>4).

namespace {

constexpr int NFFT = 4096;
constexpr int NT   = 256;
constexpr int NB   = 32;
constexpr int NC   = 64;
constexpr int KF   = 4;

typedef __fp16 h2 __attribute__((ext_vector_type(2)));
typedef float  f4 __attribute__((ext_vector_type(4)));

__device__ __forceinline__ int pad(int i) { return i + (i >> 4); }

// LDS-only barrier: wave drains its own LDS ops, then syncs. Global stores
// stay in flight across it.
__device__ __forceinline__ void lds_barrier(){
    asm volatile("s_waitcnt lgkmcnt(0)" ::: "memory");
    __builtin_amdgcn_s_barrier();
}

__device__ __forceinline__ unsigned packh(float x, float y){
    h2 h = __builtin_amdgcn_cvt_pkrtz(x, y);   // v_cvt_pkrtz_f16_f32
    return __builtin_bit_cast(unsigned, h);
}
__device__ __forceinline__ float2 unpackh(unsigned u){
    h2 h = __builtin_bit_cast(h2, u);
    return make_float2((float)h.x, (float)h.y);
}

__device__ __forceinline__ float2 cadd(float2 a, float2 b){ return make_float2(a.x+b.x, a.y+b.y); }
__device__ __forceinline__ float2 csub(float2 a, float2 b){ return make_float2(a.x-b.x, a.y-b.y); }
__device__ __forceinline__ float2 cmul(float2 a, float2 b){
    return make_float2(fmaf(a.x,b.x,-(a.y*b.y)), fmaf(a.x,b.y, a.y*b.x));
}
// a * conj(b)
__device__ __forceinline__ float2 cmulc(float2 a, float2 b){
    return make_float2(fmaf(a.x,b.x, a.y*b.y), fmaf(a.y,b.x,-(a.x*b.y)));
}

__device__ __forceinline__ void bf4_fwd(float2&a,float2&b,float2&c,float2&d){
    float2 t0=cadd(a,c), t1=csub(a,c), t2=cadd(b,d), t3=csub(b,d);
    float2 mi3=make_float2(t3.y,-t3.x);          // -i*t3
    a=cadd(t0,t2); b=cadd(t1,mi3); c=csub(t0,t2); d=csub(t1,mi3);
}
__device__ __forceinline__ void bf4_inv(float2&a,float2&b,float2&c,float2&d){
    float2 t0=cadd(a,c), t1=csub(a,c), t2=cadd(b,d), t3=csub(b,d);
    float2 pi3=make_float2(-t3.y,t3.x);          // +i*t3
    a=cadd(t0,t2); b=cadd(t1,pi3); c=csub(t0,t2); d=csub(t1,pi3);
}
__device__ __forceinline__ void grp_fwd(float2&a,float2&b,float2&c,float2&d,
                                        float2 w1, float2 w2, float2 w3){
    bf4_fwd(a,b,c,d);
    b=cmul(b,w1); c=cmul(c,w2); d=cmul(d,w3);
}
__device__ __forceinline__ void xgrp_fwd(float2&a,float2&b,float2&c,float2&d, float2 w1){
    float2 w2=cmul(w1,w1), w3=cmul(w2,w1);
    grp_fwd(a,b,c,d,w1,w2,w3);
}
__device__ __forceinline__ void grp_inv(float2&a,float2&b,float2&c,float2&d,
                                        float2 w1, float2 w2, float2 w3){
    b=cmulc(b,w1); c=cmulc(c,w2); d=cmulc(d,w3);
    bf4_inv(a,b,c,d);
}
__device__ __forceinline__ void xgrp_inv(float2&a,float2&b,float2&c,float2&d, float2 w1){
    float2 w2=cmul(w1,w1), w3=cmul(w2,w1);
    grp_inv(a,b,c,d,w1,w2,w3);
}

// ========== Fused kernel: fill + forward + 4x(mask + inverse) ==========
// COAL=true: dense fp16 rows to ws2[k][b][pair][t]. false: scattered f32 out.
template<bool COAL>
__global__ __launch_bounds__(NT)
void dfl_fused(const float* __restrict__ x,
               const int* __restrict__ taus,
               const int* __restrict__ mus,
               float* __restrict__ out,
               unsigned* __restrict__ ws2)
{
    __shared__ unsigned bufh[NFFT + NFFT/16];   // 17408 B, half2-packed
    __shared__ unsigned spech[NFFT + NFFT/16];  // 17408 B, half2-packed park
    __shared__ float2 wtab[512];                // 4096 B  (total 38912)

    const int tid = threadIdx.x;
    const int l    = ((blockIdx.x & 7) << 7) | (blockIdx.x >> 3);  // XCD swizzle
    const int b    = l >> 5;
    const int pair = l & 31;
    const int c0   = pair << 1;
    const float QNAN = __uint_as_float(0x7fc00000u);

    // w(j) = exp(-2*pi*i*j/4096), j<512
    for (int j = tid; j < 512; j += NT) {
        float s, c; sincosf(-3.14159265358979f * (float)j / 2048.0f, &s, &c);
        wtab[j] = make_float2(c, s);
    }

    // scan scratch aliases the (not-yet-used) spectrum region
    float2* chLast  = reinterpret_cast<float2*>(spech);        // [256]
    float2* chFirst = reinterpret_cast<float2*>(spech) + 256;  // [256]

    // ---- load + in-chunk forward fill (thread t owns times [16t,16t+16)) ----
    const float* xb = x + ((size_t)b * NFFT) * NC + c0;
    float2 z[16];
    float2 last = make_float2(QNAN, QNAN), first = make_float2(QNAN, QNAN);
    #pragma unroll
    for (int j = 0; j < 16; ++j) {
        float2 v = *reinterpret_cast<const float2*>(xb + (size_t)(16*tid + j) * NC);
        if (first.x != first.x && v.x == v.x) first.x = v.x;
        if (first.y != first.y && v.y == v.y) first.y = v.y;
        if (v.x == v.x) last.x = v.x; else v.x = last.x;
        if (v.y == v.y) last.y = v.y; else v.y = last.y;
        z[j] = v;                               // NaN only in leading run
    }
    chLast[tid] = last;
    chFirst[tid] = first;
    lds_barrier();                              // S1: scans visible

    // last observed before this chunk
    float2 pre = make_float2(QNAN, QNAN);
    for (int kk = tid - 1; kk >= 0; --kk) {
        float2 s2 = chLast[kk];
        if (pre.x != pre.x) pre.x = s2.x;
        if (pre.y != pre.y) pre.y = s2.y;
        if (pre.x == pre.x && pre.y == pre.y) break;
    }
    // globally first observed (backward-fill value for the leading prefix)
    float2 gfirst = make_float2(QNAN, QNAN);
    for (int kk = 0; kk < NT; ++kk) {
        float2 s2 = chFirst[kk];
        if (gfirst.x != gfirst.x) gfirst.x = s2.x;
        if (gfirst.y != gfirst.y) gfirst.y = s2.y;
        if (gfirst.x == gfirst.x && gfirst.y == gfirst.y) break;
    }
    if (gfirst.x != gfirst.x) gfirst.x = 0.f;   // all-NaN -> 0
    if (gfirst.y != gfirst.y) gfirst.y = 0.f;
    const float fx = (pre.x == pre.x) ? pre.x : gfirst.x;
    const float fy = (pre.y == pre.y) ? pre.y : gfirst.y;
    const float scale = 1.0f / (float)NFFT;     // prescale -> fp16-safe range
    #pragma unroll
    for (int j = 0; j < 16; ++j) {
        if (z[j].x != z[j].x) z[j].x = fx;
        if (z[j].y != z[j].y) z[j].y = fy;
        z[j].x *= scale; z[j].y *= scale;
    }

    // ---- per-thread twiddle bases ----
    const float2 wm = wtab[tid];                        // w(m)
    float2 q2 = cmul(wm, wm);
    const float2 w4m = cmul(q2, q2);                    // w(4m)
    const float2 w16r = wtab[16 * (tid & 15)];          // w(16r)
    float2 q3 = cmul(w16r, w16r);
    const float2 w64r = cmul(q3, q3);                   // w(64r)

    const float2 W1 = make_float2( 0.92387953251f,-0.38268343236f); // w(256)
    const float2 W2 = make_float2( 0.70710678119f,-0.70710678119f); // w(512)
    const float2 W3 = make_float2( 0.38268343236f,-0.92387953251f); // w(768)
    const float2 W4 = make_float2( 0.f,-1.f);                       // w(1024)
    const float2 W6 = make_float2(-0.70710678119f,-0.70710678119f); // w(1536)
    const float2 W9 = make_float2(-0.92387953251f, 0.38268343236f); // w(2304)

    // ---- write x_clean/N at P3 (natural time), fp16-packed. bufh is NOT
    // the scan buffer (spech), so one barrier covers scan-reads-done AND
    // bufh-visibility: S2+S3 merged.
    #pragma unroll
    for (int j = 0; j < 16; ++j) bufh[pad(16*tid + j)] = packh(z[j].x, z[j].y);
    lds_barrier();                              // S2/S3 merged

    // ================= forward DIF =================
    // phase A on P1 (n = m + 256j)
    #pragma unroll
    for (int j = 0; j < 16; ++j) z[j] = unpackh(bufh[pad(tid + 256*j)]);
    xgrp_fwd(z[0],z[4],z[8],z[12], wm);
    xgrp_fwd(z[1],z[5],z[9],z[13], cmul(wm,W1));
    xgrp_fwd(z[2],z[6],z[10],z[14], cmul(wm,W2));
    xgrp_fwd(z[3],z[7],z[11],z[15], cmul(wm,W3));
    {   float2 w1=w4m, w2=cmul(w1,w1), w3=cmul(w2,w1);
        grp_fwd(z[0],z[1],z[2],z[3],  w1,w2,w3);
        grp_fwd(z[4],z[5],z[6],z[7],  w1,w2,w3);
        grp_fwd(z[8],z[9],z[10],z[11],w1,w2,w3);
        grp_fwd(z[12],z[13],z[14],z[15],w1,w2,w3);
    }
    #pragma unroll
    for (int j = 0; j < 16; ++j) bufh[pad(tid + 256*j)] = packh(z[j].x, z[j].y);
    lds_barrier();                              // S4

    // phase B on P2 (n = (m>>4)*256 + (m&15) + 16j)
    const int p2b = ((tid >> 4) << 8) + (tid & 15);
    #pragma unroll
    for (int j = 0; j < 16; ++j) z[j] = unpackh(bufh[pad(p2b + 16*j)]);
    xgrp_fwd(z[0],z[4],z[8],z[12], w16r);
    xgrp_fwd(z[1],z[5],z[9],z[13], cmul(w16r,W1));
    xgrp_fwd(z[2],z[6],z[10],z[14], cmul(w16r,W2));
    xgrp_fwd(z[3],z[7],z[11],z[15], cmul(w16r,W3));
    {   float2 w1=w64r, w2=cmul(w1,w1), w3=cmul(w2,w1);
        grp_fwd(z[0],z[1],z[2],z[3],  w1,w2,w3);
        grp_fwd(z[4],z[5],z[6],z[7],  w1,w2,w3);
        grp_fwd(z[8],z[9],z[10],z[11],w1,w2,w3);
        grp_fwd(z[12],z[13],z[14],z[15],w1,w2,w3);
    }
    #pragma unroll
    for (int j = 0; j < 16; ++j) bufh[pad(p2b + 16*j)] = packh(z[j].x, z[j].y);
    lds_barrier();                              // S5

    // phase C on P3 (n = 16m + j)
    #pragma unroll
    for (int j = 0; j < 16; ++j) z[j] = unpackh(bufh[pad(16*tid + j)]);
    bf4_fwd(z[0],z[4],z[8],z[12]);
    grp_fwd(z[1],z[5],z[9],z[13], W1,W2,W3);
    grp_fwd(z[2],z[6],z[10],z[14], W2,W4,W6);
    grp_fwd(z[3],z[7],z[11],z[15], W3,W6,W9);
    bf4_fwd(z[0],z[1],z[2],z[3]);
    bf4_fwd(z[4],z[5],z[6],z[7]);
    bf4_fwd(z[8],z[9],z[10],z[11]);
    bf4_fwd(z[12],z[13],z[14],z[15]);

    // ---- park spectrum (already /N) in LDS, fp16-packed, own P3 slots ----
    #pragma unroll
    for (int j = 0; j < 16; ++j) spech[pad(16*tid + j)] = packh(z[j].x, z[j].y);

    // digit-reverse of tid (4 base-4 digits)
    const int revtid = ((tid & 3) << 6) | (((tid >> 2) & 3) << 4)
                     | (((tid >> 4) & 3) << 2) | (tid >> 6);

    // ================= per-filter inverse DIT =================
    #pragma unroll 1
    for (int k = 0; k < KF; ++k) {
        const int tau = taus[k];
        const int mu  = mus[k];

        // mask + unpack + stage0 + stage1 BEFORE the barrier: these touch
        // only own-thread spech slots (phase C / prior filters read bufh,
        // own P3 spech slots are stable) -> overlaps other waves' barrier
        // arrival from the previous filter's P1 reads.
        #pragma unroll
        for (int j = 0; j < 16; ++j) {
            const int r = revtid + ((j & 3) << 10) + ((j >> 2) << 8);
            const int f = (r <= 2048) ? r : (NFFT - r);
            const bool keep = (mu == 1) ? (f < tau) : (f >= tau);
            z[j] = keep ? unpackh(spech[pad(16*tid + j)]) : make_float2(0.f, 0.f);
        }
        // stage0: Y-groups, no twiddle
        bf4_inv(z[0],z[1],z[2],z[3]);
        bf4_inv(z[4],z[5],z[6],z[7]);
        bf4_inv(z[8],z[9],z[10],z[11]);
        bf4_inv(z[12],z[13],z[14],z[15]);
        // stage1: X-groups, k1 = 256*jp (constants)
        bf4_inv(z[0],z[4],z[8],z[12]);
        grp_inv(z[1],z[5],z[9],z[13], W1,W2,W3);
        grp_inv(z[2],z[6],z[10],z[14], W2,W4,W6);
        grp_inv(z[3],z[7],z[11],z[15], W3,W6,W9);

        lds_barrier();          // previous filter's P1 reads done everywhere
        #pragma unroll
        for (int j = 0; j < 16; ++j) bufh[pad(16*tid + j)] = packh(z[j].x, z[j].y);
        lds_barrier();

        #pragma unroll
        for (int j = 0; j < 16; ++j) z[j] = unpackh(bufh[pad(p2b + 16*j)]);
        // stage2: Y-groups, k1 = 64r
        {   float2 w1=w64r, w2=cmul(w1,w1), w3=cmul(w2,w1);
            grp_inv(z[0],z[1],z[2],z[3],  w1,w2,w3);
            grp_inv(z[4],z[5],z[6],z[7],  w1,w2,w3);
            grp_inv(z[8],z[9],z[10],z[11],w1,w2,w3);
            grp_inv(z[12],z[13],z[14],z[15],w1,w2,w3);
        }
        // stage3: X-groups, k1 = 16r + 256*jp
        xgrp_inv(z[0],z[4],z[8],z[12], w16r);
        xgrp_inv(z[1],z[5],z[9],z[13], cmul(w16r,W1));
        xgrp_inv(z[2],z[6],z[10],z[14], cmul(w16r,W2));
        xgrp_inv(z[3],z[7],z[11],z[15], cmul(w16r,W3));
        #pragma unroll
        for (int j = 0; j < 16; ++j) bufh[pad(p2b + 16*j)] = packh(z[j].x, z[j].y);
        lds_barrier();

        #pragma unroll
        for (int j = 0; j < 16; ++j) z[j] = unpackh(bufh[pad(tid + 256*j)]);
        // stage4: Y-groups, k1 = 4m
        {   float2 w1=w4m, w2=cmul(w1,w1), w3=cmul(w2,w1);
            grp_inv(z[0],z[1],z[2],z[3],  w1,w2,w3);
            grp_inv(z[4],z[5],z[6],z[7],  w1,w2,w3);
            grp_inv(z[8],z[9],z[10],z[11],w1,w2,w3);
            grp_inv(z[12],z[13],z[14],z[15],w1,w2,w3);
        }
        // stage5: X-groups, k1 = m + 256*jp
        xgrp_inv(z[0],z[4],z[8],z[12], wm);
        xgrp_inv(z[1],z[5],z[9],z[13], cmul(wm,W1));
        xgrp_inv(z[2],z[6],z[10],z[14], cmul(wm,W2));
        xgrp_inv(z[3],z[7],z[11],z[15], cmul(wm,W3));

        if (COAL) {
            // dense fp16 row [k][b][pair][t]; 256B contiguous per wave-inst;
            // stays in flight across the next filter's lds_barrier
            unsigned* orow = ws2 + ((size_t)((k*NB + b)*32 + pair)) * NFFT;
            #pragma unroll
            for (int j = 0; j < 16; ++j)
                orow[tid + 256*j] = packh(z[j].x, z[j].y);
        } else {
            float* ob = out + ((size_t)(k*NB + b) * NFFT) * NC + c0;
            #pragma unroll
            for (int j = 0; j < 16; ++j) {
                const int t = tid + 256*j;
                *reinterpret_cast<float2*>(ob + (size_t)t * NC) = z[j];
            }
        }
    }
}

// ===================== transpose-expand =====================
// ws2[k][b][pair][t] fp16-packed -> out[k][b][t][c] f32, all coalesced.
__global__ __launch_bounds__(NT)
void dfl_expand(const unsigned* __restrict__ ws2, float* __restrict__ out)
{
    __shared__ unsigned tile[32][257];          // 32 pairs x 256 t (+pad)

    const int tid = threadIdx.x;
    const int wg  = ((blockIdx.x & 7) << 8) | (blockIdx.x >> 3);  // XCD swizzle
    const int tb  = wg & 15;                    // t-block (256 t each)
    const int kb  = wg >> 4;                    // k*NB + b, 0..127
    const int t0  = tb << 8;

    const unsigned* src = ws2 + ((size_t)kb * 32) * NFFT + t0;
    // load 32 rows x 256 u32 as uint4 (16B/lane, dense)
    #pragma unroll
    for (int i = 0; i < 8; ++i) {
        const int g   = i * NT + tid;           // uint4 index, 0..2047
        const int row = g >> 6;                 // 64 uint4 per row
        const int t4  = (g & 63) << 2;
        uint4 v = *reinterpret_cast<const uint4*>(src + (size_t)row * NFFT + t4);
        tile[row][t4+0] = v.x; tile[row][t4+1] = v.y;
        tile[row][t4+2] = v.z; tile[row][t4+3] = v.w;
    }
    __syncthreads();

    // store: out rows, float4 = 4 channels (2 pairs) per lane; a wave covers
    // 4 full t-rows = 1KiB contiguous. Nontemporal: out is never re-read.
    float* ob = out + ((size_t)kb * NFFT + t0) * NC;
    #pragma unroll
    for (int j = 0; j < 16; ++j) {
        const int g    = j * NT + tid;          // float4 index, 0..4095
        const int tloc = g >> 4;                // 16 float4 per t-row
        const int q    = g & 15;                // pair-pair index
        float2 a  = unpackh(tile[2*q    ][tloc]);
        float2 bb = unpackh(tile[2*q + 1][tloc]);
        f4 v = {a.x, a.y, bb.x, bb.y};
        __builtin_nontemporal_store(
            v, reinterpret_cast<f4*>(ob + (size_t)tloc * NC + 4*q));
    }
}

} // namespace

extern "C" void kernel_launch(void* const* d_in, const int* in_sizes, int n_in,
                              void* d_out, int out_size, void* d_ws, size_t ws_size,
                              hipStream_t stream) {
    (void)in_sizes; (void)n_in; (void)out_size;
    const float* x  = (const float*)d_in[0];
    const int* taus = (const int*)d_in[1];
    const int* mus  = (const int*)d_in[2];
    float* out      = (float*)d_out;
    unsigned* ws2   = (unsigned*)d_ws;          // staging: 64 MiB
    const size_t need = (size_t)64 << 20;

    if (ws_size >= need) {
        dfl_fused<true><<<dim3(NB * NC / 2), dim3(NT), 0, stream>>>(
            x, taus, mus, out, ws2);
        dfl_expand<<<dim3(KF * NB * 16), dim3(NT), 0, stream>>>(ws2, out);
    } else {
        dfl_fused<false><<<dim3(NB * NC / 2), dim3(NT), 0, stream>>>(
            x, taus, mus, out, nullptr);
    }
}